// Round 1
// baseline (4558.119 us; speedup 1.0000x reference)
//
#include <hip/hip_runtime.h>
#include <math.h>

#define S_LEN   2048
#define BATCH   2
#define HIDDEN  1024
#define NTOK    (S_LEN*BATCH)      // 4096
#define QKV_OUT 2048
#define N_HEADS 16
#define HEAD_DIM 64
#define N_EXP   8
#define CAP     1280               // ceil(4096*2/8*1.25)
#define NSLOT   (N_EXP*CAP)        // 10240
#define FFN     4096
#define NFLAT   (NTOK*2)           // 8192
#define NCHUNK  (NFLAT/64)         // 128

// ---------------- LayerNorm (one block per token) ----------------
__global__ __launch_bounds__(256) void ln_kernel(const float* __restrict__ in,
    const float* __restrict__ w, const float* __restrict__ b, float* __restrict__ out) {
  int n = blockIdx.x;
  const float* row = in + (size_t)n * HIDDEN;
  float v[4];
  float s = 0.f, s2 = 0.f;
#pragma unroll
  for (int i = 0; i < 4; i++) {
    v[i] = row[threadIdx.x + 256 * i];
    s += v[i]; s2 += v[i] * v[i];
  }
#pragma unroll
  for (int off = 32; off; off >>= 1) { s += __shfl_xor(s, off); s2 += __shfl_xor(s2, off); }
  __shared__ float ss[4], ss2[4];
  int wave = threadIdx.x >> 6;
  if ((threadIdx.x & 63) == 0) { ss[wave] = s; ss2[wave] = s2; }
  __syncthreads();
  s = ss[0] + ss[1] + ss[2] + ss[3];
  s2 = ss2[0] + ss2[1] + ss2[2] + ss2[3];
  float mu = s * (1.f / HIDDEN);
  float var = s2 * (1.f / HIDDEN) - mu * mu;
  float r = rsqrtf(var + 1e-5f);
#pragma unroll
  for (int i = 0; i < 4; i++) {
    int c = threadIdx.x + 256 * i;
    out[(size_t)n * HIDDEN + c] = (v[i] - mu) * r * w[c] + b[c];
  }
}

// ---------------- GEMM: C[M,N] = A[M,K] @ B[N,K]^T (+ optional residual R[M,N]) ----------------
template<bool ADD_RES>
__global__ __launch_bounds__(256) void gemm_nt(const float* __restrict__ A,
    const float* __restrict__ B, const float* __restrict__ R, float* __restrict__ C,
    int N, int K) {
  __shared__ float As[16][68];
  __shared__ float Bs[16][68];
  int bx = blockIdx.x, by = blockIdx.y;
  int tid = threadIdx.x;
  int tx = tid & 15, ty = tid >> 4;
  int row0 = by * 64, col0 = bx * 64;
  float acc[4][4] = {};
  for (int k0 = 0; k0 < K; k0 += 16) {
#pragma unroll
    for (int i = 0; i < 4; i++) {
      int idx = tid + 256 * i;
      int r = idx >> 4, c = idx & 15;
      As[c][r] = A[(size_t)(row0 + r) * K + k0 + c];
      Bs[c][r] = B[(size_t)(col0 + r) * K + k0 + c];
    }
    __syncthreads();
#pragma unroll
    for (int kk = 0; kk < 16; kk++) {
      float a[4], bv[4];
#pragma unroll
      for (int i = 0; i < 4; i++) a[i] = As[kk][ty * 4 + i];
#pragma unroll
      for (int j = 0; j < 4; j++) bv[j] = Bs[kk][tx * 4 + j];
#pragma unroll
      for (int i = 0; i < 4; i++)
#pragma unroll
        for (int j = 0; j < 4; j++) acc[i][j] += a[i] * bv[j];
    }
    __syncthreads();
  }
#pragma unroll
  for (int i = 0; i < 4; i++) {
    int r = row0 + ty * 4 + i;
#pragma unroll
    for (int j = 0; j < 4; j++) {
      int c = col0 + tx * 4 + j;
      float v = acc[i][j];
      if (ADD_RES) v += R[(size_t)r * N + c];
      C[(size_t)r * N + c] = v;
    }
  }
}

// ---------------- Flash attention, causal GQA, fp32 ----------------
// block: 256 threads = 64 q-rows x 4 lanes (each lane owns 16 of 64 dims)
__global__ __launch_bounds__(256) void attn_kernel(const float* __restrict__ qkv,
                                                   float* __restrict__ attn_out) {
  int qt = blockIdx.x, h = blockIdx.y, b = blockIdx.z;
  int g = h >> 1;
  int qcol = g * 256 + (h & 1) * 64;
  int kcol = g * 256 + 128;
  int vcol = g * 256 + 192;
  int tid = threadIdx.x;
  int r = tid >> 2, p = tid & 3;
  int sq = qt * 64 + r;
  __shared__ float Kt[64][68];
  __shared__ float Vt[64][68];
  float qv[16], o[16];
  const float* qrow = qkv + ((size_t)sq * BATCH + b) * QKV_OUT + qcol + p * 16;
#pragma unroll
  for (int i = 0; i < 16; i++) { qv[i] = qrow[i]; o[i] = 0.f; }
  float m = -1e30f, l = 0.f;
  for (int kt = 0; kt <= qt; kt++) {
#pragma unroll
    for (int i = 0; i < 16; i++) {
      int idx = tid + 256 * i;
      int rr = idx >> 6, cc = idx & 63;
      size_t base = ((size_t)(kt * 64 + rr) * BATCH + b) * QKV_OUT;
      Kt[rr][cc] = qkv[base + kcol + cc];
      Vt[rr][cc] = qkv[base + vcol + cc];
    }
    __syncthreads();
    float s[64];
#pragma unroll
    for (int j = 0; j < 64; j++) {
      float accd = 0.f;
#pragma unroll
      for (int i = 0; i < 16; i++) accd += qv[i] * Kt[j][p * 16 + i];
      accd += __shfl_xor(accd, 1);
      accd += __shfl_xor(accd, 2);
      s[j] = accd;
    }
    int kbase = kt * 64;
    float mt = -1e30f;
#pragma unroll
    for (int j = 0; j < 64; j++) {
      bool valid = (kbase + j) <= sq;
      s[j] = valid ? s[j] * 0.125f : -1e30f;
      mt = fmaxf(mt, s[j]);
    }
    float mn = fmaxf(m, mt);
    float corr = __expf(m - mn);
    l *= corr;
#pragma unroll
    for (int i = 0; i < 16; i++) o[i] *= corr;
#pragma unroll
    for (int j = 0; j < 64; j++) {
      float pj = __expf(s[j] - mn);
      l += pj;
#pragma unroll
      for (int i = 0; i < 16; i++) o[i] += pj * Vt[j][p * 16 + i];
    }
    m = mn;
    __syncthreads();
  }
  float inv = 1.f / l;
  float* orow = attn_out + ((size_t)sq * BATCH + b) * HIDDEN + h * 64 + p * 16;
#pragma unroll
  for (int i = 0; i < 16; i++) orow[i] = o[i] * inv;
}

// ---------------- Router: logits, softmax, top-2, renormalize ----------------
__global__ __launch_bounds__(64) void router_kernel(const float* __restrict__ x,
    const float* __restrict__ wr, float* __restrict__ top_p, int* __restrict__ top_i) {
  int n = blockIdx.x;
  int lane = threadIdx.x;
  float acc[N_EXP];
#pragma unroll
  for (int e = 0; e < N_EXP; e++) acc[e] = 0.f;
  const float* xr = x + (size_t)n * HIDDEN;
  for (int hh = lane; hh < HIDDEN; hh += 64) {
    float xv = xr[hh];
    const float* wrow = wr + (size_t)hh * N_EXP;
#pragma unroll
    for (int e = 0; e < N_EXP; e++) acc[e] += xv * wrow[e];
  }
#pragma unroll
  for (int off = 32; off; off >>= 1)
#pragma unroll
    for (int e = 0; e < N_EXP; e++) acc[e] += __shfl_xor(acc[e], off);
  if (lane == 0) {
    float mx = acc[0];
#pragma unroll
    for (int e = 1; e < N_EXP; e++) mx = fmaxf(mx, acc[e]);
    float pr[N_EXP]; float ssum = 0.f;
#pragma unroll
    for (int e = 0; e < N_EXP; e++) { pr[e] = __expf(acc[e] - mx); ssum += pr[e]; }
    float inv = 1.f / ssum;
#pragma unroll
    for (int e = 0; e < N_EXP; e++) pr[e] *= inv;
    int i0 = 0; float p0 = pr[0];
#pragma unroll
    for (int e = 1; e < N_EXP; e++) if (pr[e] > p0) { p0 = pr[e]; i0 = e; }
    int i1 = -1; float p1 = -1.f;
#pragma unroll
    for (int e = 0; e < N_EXP; e++) if (e != i0 && pr[e] > p1) { p1 = pr[e]; i1 = e; }
    float norm = 1.f / (p0 + p1);
    top_p[n * 2] = p0 * norm;
    top_p[n * 2 + 1] = p1 * norm;
    top_i[n * 2] = i0;
    top_i[n * 2 + 1] = i1;
  }
}

// ---------------- Dispatch: stable per-expert rank (== stable argsort by expert) ----------------
__global__ __launch_bounds__(64) void hist_kernel(const int* __restrict__ top_i,
    int* __restrict__ counts, int* __restrict__ wloc) {
  int i = blockIdx.x * 64 + threadIdx.x;
  int e = top_i[i];
  unsigned long long lower = (threadIdx.x == 0) ? 0ull : ((1ull << threadIdx.x) - 1ull);
  int wl = 0;
#pragma unroll
  for (int ex = 0; ex < N_EXP; ex++) {
    unsigned long long mmask = __ballot(e == ex);
    if (e == ex) wl = __popcll(mmask & lower);
    if ((int)threadIdx.x == ex) counts[blockIdx.x * N_EXP + ex] = __popcll(mmask);
  }
  wloc[i] = wl;
}

__global__ __launch_bounds__(64) void scan_kernel(const int* __restrict__ counts,
                                                  int* __restrict__ cbase) {
  int e = threadIdx.x;
  if (e < N_EXP) {
    int run = 0;
    for (int c = 0; c < NCHUNK; c++) {
      cbase[c * N_EXP + e] = run;
      run += counts[c * N_EXP + e];
    }
  }
}

__global__ __launch_bounds__(256) void assign_kernel(const int* __restrict__ top_i,
    const int* __restrict__ cbase, const int* __restrict__ wloc,
    int* __restrict__ soe, int* __restrict__ dtok) {
  int i = blockIdx.x * 256 + threadIdx.x;
  int e = top_i[i];
  int w = cbase[(i >> 6) * N_EXP + e] + wloc[i];
  if (w < CAP) {
    int slot = e * CAP + w;
    soe[i] = slot;
    dtok[slot] = i >> 1;
  } else {
    soe[i] = -1;
  }
}

// ---------------- MoE GEMM1: act[slot][f] = gelu(sum_h x[tok[slot]][h] * w1[e][h][f]) ----------------
__global__ __launch_bounds__(256) void moe_gemm1(const float* __restrict__ x,
    const int* __restrict__ tok, const float* __restrict__ w1, float* __restrict__ act,
    int slot0, int actSlot0) {
  __shared__ float As[16][68];
  __shared__ float Bs[16][68];
  int bx = blockIdx.x, by = blockIdx.y;
  int slotBlock = slot0 + by * 64;
  int e = slotBlock / CAP;
  const float* B = w1 + (size_t)e * HIDDEN * FFN;
  int col0 = bx * 64;
  int tid = threadIdx.x;
  int tx = tid & 15, ty = tid >> 4;
  int tokR[4];
#pragma unroll
  for (int i = 0; i < 4; i++) {
    int r = (tid + 256 * i) >> 4;
    tokR[i] = tok[slotBlock + r];
  }
  float acc[4][4] = {};
  for (int k0 = 0; k0 < HIDDEN; k0 += 16) {
#pragma unroll
    for (int i = 0; i < 4; i++) {
      int idx = tid + 256 * i;
      int r = idx >> 4, c = idx & 15;
      As[c][r] = x[(size_t)tokR[i] * HIDDEN + k0 + c];
    }
#pragma unroll
    for (int i = 0; i < 4; i++) {
      int idx = tid + 256 * i;
      int r = idx & 63, c = idx >> 6;
      Bs[c][r] = B[(size_t)(k0 + c) * FFN + col0 + r];
    }
    __syncthreads();
#pragma unroll
    for (int kk = 0; kk < 16; kk++) {
      float a[4], bv[4];
#pragma unroll
      for (int i = 0; i < 4; i++) a[i] = As[kk][ty * 4 + i];
#pragma unroll
      for (int j = 0; j < 4; j++) bv[j] = Bs[kk][tx * 4 + j];
#pragma unroll
      for (int i = 0; i < 4; i++)
#pragma unroll
        for (int j = 0; j < 4; j++) acc[i][j] += a[i] * bv[j];
    }
    __syncthreads();
  }
#pragma unroll
  for (int i = 0; i < 4; i++) {
    int rl = slotBlock - actSlot0 + ty * 4 + i;
#pragma unroll
    for (int j = 0; j < 4; j++) {
      float v = acc[i][j];
      v = 0.5f * v * (1.f + erff(v * 0.70710678118654752f));
      act[(size_t)rl * FFN + col0 + tx * 4 + j] = v;
    }
  }
}

// ---------------- MoE GEMM2: expo[slot][h] = sum_f act[slot][f] * w2[e][f][h] ----------------
__global__ __launch_bounds__(256) void moe_gemm2(const float* __restrict__ act,
    const float* __restrict__ w2, float* __restrict__ expo, int slot0, int actSlot0) {
  __shared__ float As[16][68];
  __shared__ float Bs[16][68];
  int bx = blockIdx.x, by = blockIdx.y;
  int slotBlock = slot0 + by * 64;
  int e = slotBlock / CAP;
  const float* B = w2 + (size_t)e * FFN * HIDDEN;
  int col0 = bx * 64;
  int tid = threadIdx.x;
  int tx = tid & 15, ty = tid >> 4;
  float acc[4][4] = {};
  for (int k0 = 0; k0 < FFN; k0 += 16) {
#pragma unroll
    for (int i = 0; i < 4; i++) {
      int idx = tid + 256 * i;
      int r = idx >> 4, c = idx & 15;
      As[c][r] = act[(size_t)(slotBlock - actSlot0 + r) * FFN + k0 + c];
    }
#pragma unroll
    for (int i = 0; i < 4; i++) {
      int idx = tid + 256 * i;
      int r = idx & 63, c = idx >> 6;
      Bs[c][r] = B[(size_t)(k0 + c) * HIDDEN + col0 + r];
    }
    __syncthreads();
#pragma unroll
    for (int kk = 0; kk < 16; kk++) {
      float a[4], bv[4];
#pragma unroll
      for (int i = 0; i < 4; i++) a[i] = As[kk][ty * 4 + i];
#pragma unroll
      for (int j = 0; j < 4; j++) bv[j] = Bs[kk][tx * 4 + j];
#pragma unroll
      for (int i = 0; i < 4; i++)
#pragma unroll
        for (int j = 0; j < 4; j++) acc[i][j] += a[i] * bv[j];
    }
    __syncthreads();
  }
#pragma unroll
  for (int i = 0; i < 4; i++) {
    int r = slotBlock + ty * 4 + i;
#pragma unroll
    for (int j = 0; j < 4; j++) {
      expo[(size_t)r * HIDDEN + col0 + tx * 4 + j] = acc[i][j];
    }
  }
}

// ---------------- Combine: out = hatt + sum_k p_k * expo[slot_k] ----------------
__global__ __launch_bounds__(256) void combine_kernel(const float* __restrict__ hatt,
    const float* __restrict__ expo, const int* __restrict__ soe,
    const float* __restrict__ top_p, float* __restrict__ out) {
  int n = blockIdx.x;
  int s0 = soe[2 * n], s1 = soe[2 * n + 1];
  float p0 = top_p[2 * n], p1 = top_p[2 * n + 1];
#pragma unroll
  for (int i = 0; i < 4; i++) {
    int c = threadIdx.x + 256 * i;
    float v = hatt[(size_t)n * HIDDEN + c];
    if (s0 >= 0) v += p0 * expo[(size_t)s0 * HIDDEN + c];
    if (s1 >= 0) v += p1 * expo[(size_t)s1 * HIDDEN + c];
    out[(size_t)n * HIDDEN + c] = v;
  }
}

extern "C" void kernel_launch(void* const* d_in, const int* in_sizes, int n_in,
                              void* d_out, int out_size, void* d_ws, size_t ws_size,
                              hipStream_t stream) {
  const float* hidden = (const float*)d_in[0];
  const float* ln1w = (const float*)d_in[1];
  const float* ln1b = (const float*)d_in[2];
  const float* ln2w = (const float*)d_in[3];
  const float* ln2b = (const float*)d_in[4];
  const float* qkvW = (const float*)d_in[5];
  const float* projW = (const float*)d_in[6];
  const float* routW = (const float*)d_in[7];
  const float* w1 = (const float*)d_in[8];
  const float* w2 = (const float*)d_in[9];
  float* out = (float*)d_out;
  float* ws = (float*)d_ws;

  size_t o = 0;
  float* ln1 = ws + o; o += (size_t)NTOK * HIDDEN;
  float* qkv = ws + o; o += (size_t)NTOK * QKV_OUT;
  float* attn = ws + o; o += (size_t)NTOK * HIDDEN;
  float* hatt = ws + o; o += (size_t)NTOK * HIDDEN;
  float* x2 = ws + o; o += (size_t)NTOK * HIDDEN;
  float* expo = ws + o; o += (size_t)NSLOT * HIDDEN;
  float* topp = ws + o; o += NFLAT;
  int* topi = (int*)(ws + o);
  int* counts = topi + NFLAT;
  int* cbase = counts + NCHUNK * N_EXP;
  int* wloc = cbase + NCHUNK * N_EXP;
  int* soe = wloc + NFLAT;
  int* dtok = soe + NFLAT;
  size_t n_ints = (size_t)NFLAT * 3 + 2 * NCHUNK * N_EXP + NSLOT;
  o += (n_ints + 255) & ~(size_t)255;
  float* act = ws + o;
  size_t need_full = (o + (size_t)NSLOT * FFN) * sizeof(float);
  bool full = ws_size >= need_full;

  hipMemsetAsync(dtok, 0, NSLOT * sizeof(int), stream);

  ln_kernel<<<NTOK, 256, 0, stream>>>(hidden, ln1w, ln1b, ln1);
  gemm_nt<false><<<dim3(QKV_OUT / 64, NTOK / 64), 256, 0, stream>>>(ln1, qkvW, nullptr, qkv, QKV_OUT, HIDDEN);
  attn_kernel<<<dim3(S_LEN / 64, N_HEADS, BATCH), 256, 0, stream>>>(qkv, attn);
  gemm_nt<true><<<dim3(HIDDEN / 64, NTOK / 64), 256, 0, stream>>>(attn, projW, hidden, hatt, HIDDEN, HIDDEN);
  ln_kernel<<<NTOK, 256, 0, stream>>>(hatt, ln2w, ln2b, x2);
  router_kernel<<<NTOK, 64, 0, stream>>>(x2, routW, topp, topi);
  hist_kernel<<<NCHUNK, 64, 0, stream>>>(topi, counts, wloc);
  scan_kernel<<<1, 64, 0, stream>>>(counts, cbase);
  assign_kernel<<<NFLAT / 256, 256, 0, stream>>>(topi, cbase, wloc, soe, dtok);

  if (full) {
    moe_gemm1<<<dim3(FFN / 64, NSLOT / 64), 256, 0, stream>>>(x2, dtok, w1, act, 0, 0);
    moe_gemm2<<<dim3(HIDDEN / 64, NSLOT / 64), 256, 0, stream>>>(act, w2, expo, 0, 0);
  } else {
    for (int e = 0; e < N_EXP; e++) {
      moe_gemm1<<<dim3(FFN / 64, CAP / 64), 256, 0, stream>>>(x2, dtok, w1, act, e * CAP, e * CAP);
      moe_gemm2<<<dim3(HIDDEN / 64, CAP / 64), 256, 0, stream>>>(act, w2, expo, e * CAP, e * CAP);
    }
  }
  combine_kernel<<<NTOK, 256, 0, stream>>>(hatt, expo, soe, topp, out);
}

// Round 10
// 1807.286 us; speedup vs baseline: 2.5221x; 2.5221x over previous
//
#include <hip/hip_runtime.h>
#include <math.h>

#define S_LEN   2048
#define BATCH   2
#define HIDDEN  1024
#define NTOK    4096
#define QKV_OUT 2048
#define N_HEADS 16
#define N_EXP   8
#define CAP     1280
#define NSLOT   10240
#define FFN     4096
#define NFLAT   8192
#define NCHUNK  128

typedef __bf16 bf16x8 __attribute__((ext_vector_type(8)));
typedef float f32x4 __attribute__((ext_vector_type(4)));
typedef unsigned short u16x4 __attribute__((ext_vector_type(4)));

__device__ __forceinline__ unsigned short f2bu(float f) {
  union { float f; unsigned u; } v; v.f = f;
  unsigned r = v.u + 0x7fffu + ((v.u >> 16) & 1u);
  return (unsigned short)(r >> 16);
}

__device__ __forceinline__ f32x4 mfma16(bf16x8 a, bf16x8 b, f32x4 c) {
  return __builtin_amdgcn_mfma_f32_16x16x32_bf16(a, b, c, 0, 0, 0);
}

__device__ __forceinline__ void gl_lds16(const void* g, void* l) {
  __builtin_amdgcn_global_load_lds((const __attribute__((address_space(1))) void*)g,
                                   (__attribute__((address_space(3))) void*)l, 16, 0, 0);
}

// ---------------- fp32 [R][C] -> bf16 [C][R] transposed convert (per z slice) ----------------
__global__ __launch_bounds__(256) void transpose_cvt(const float* __restrict__ in,
                                                     unsigned short* __restrict__ out,
                                                     int R, int C) {
  __shared__ float t[32][33];
  int c0 = blockIdx.x * 32, r0 = blockIdx.y * 32;
  long z = (long)blockIdx.z * R * C;
  const float* inz = in + z;
  unsigned short* outz = out + z;
  int x = threadIdx.x & 31, y0 = threadIdx.x >> 5;
#pragma unroll
  for (int i = 0; i < 4; i++) {
    int r = y0 + i * 8;
    t[r][x] = inz[(long)(r0 + r) * C + c0 + x];
  }
  __syncthreads();
#pragma unroll
  for (int i = 0; i < 4; i++) {
    int r = y0 + i * 8;
    outz[(long)(c0 + r) * R + r0 + x] = f2bu(t[x][r]);
  }
}

// ---------------- LayerNorm: fp32 in, fp32 out (+ optional bf16 out) ----------------
template<bool WB16>
__global__ __launch_bounds__(256) void ln_kernel(const float* __restrict__ in,
    const float* __restrict__ w, const float* __restrict__ bia,
    float* __restrict__ outf, unsigned short* __restrict__ outb) {
  int n = blockIdx.x, tid = threadIdx.x;
  float4 v = ((const float4*)(in + (long)n * HIDDEN))[tid];
  float s = v.x + v.y + v.z + v.w;
  float s2 = v.x * v.x + v.y * v.y + v.z * v.z + v.w * v.w;
#pragma unroll
  for (int off = 32; off; off >>= 1) { s += __shfl_xor(s, off); s2 += __shfl_xor(s2, off); }
  __shared__ float ss[4], ss2[4];
  int wv = tid >> 6;
  if ((tid & 63) == 0) { ss[wv] = s; ss2[wv] = s2; }
  __syncthreads();
  s = ss[0] + ss[1] + ss[2] + ss[3];
  s2 = ss2[0] + ss2[1] + ss2[2] + ss2[3];
  float mu = s * (1.f / HIDDEN);
  float var = s2 * (1.f / HIDDEN) - mu * mu;
  float rstd = rsqrtf(var + 1e-5f);
  float4 wv4 = ((const float4*)w)[tid];
  float4 bv4 = ((const float4*)bia)[tid];
  float4 of;
  of.x = (v.x - mu) * rstd * wv4.x + bv4.x;
  of.y = (v.y - mu) * rstd * wv4.y + bv4.y;
  of.z = (v.z - mu) * rstd * wv4.z + bv4.z;
  of.w = (v.w - mu) * rstd * wv4.w + bv4.w;
  *(float4*)(outf + (long)n * HIDDEN + tid * 4) = of;
  if (WB16) {
    u16x4 ob = { f2bu(of.x), f2bu(of.y), f2bu(of.z), f2bu(of.w) };
    *(u16x4*)(outb + (long)n * HIDDEN + tid * 4) = ob;
  }
}

// ---------------- fp32 GEMM: C[M,N] = A[M,K] @ B[N,K]^T (+ optional residual) ----------------
template<bool ADD_RES>
__global__ __launch_bounds__(256) void gemm_nt(const float* __restrict__ A,
    const float* __restrict__ B, const float* __restrict__ R, float* __restrict__ C,
    int N, int K) {
  __shared__ float As[16][68];
  __shared__ float Bs[16][68];
  int bx = blockIdx.x, by = blockIdx.y;
  int tid = threadIdx.x;
  int tx = tid & 15, ty = tid >> 4;
  int row0 = by * 64, col0 = bx * 64;
  float acc[4][4] = {};
  for (int k0 = 0; k0 < K; k0 += 16) {
#pragma unroll
    for (int i = 0; i < 4; i++) {
      int idx = tid + 256 * i;
      int r = idx >> 4, c = idx & 15;
      As[c][r] = A[(size_t)(row0 + r) * K + k0 + c];
      Bs[c][r] = B[(size_t)(col0 + r) * K + k0 + c];
    }
    __syncthreads();
#pragma unroll
    for (int kk = 0; kk < 16; kk++) {
      float a[4], bv[4];
#pragma unroll
      for (int i = 0; i < 4; i++) a[i] = As[kk][ty * 4 + i];
#pragma unroll
      for (int j = 0; j < 4; j++) bv[j] = Bs[kk][tx * 4 + j];
#pragma unroll
      for (int i = 0; i < 4; i++)
#pragma unroll
        for (int j = 0; j < 4; j++) acc[i][j] += a[i] * bv[j];
    }
    __syncthreads();
  }
#pragma unroll
  for (int i = 0; i < 4; i++) {
    int r = row0 + ty * 4 + i;
#pragma unroll
    for (int j = 0; j < 4; j++) {
      int c = col0 + tx * 4 + j;
      float v = acc[i][j];
      if (ADD_RES) v += R[(size_t)r * N + c];
      C[(size_t)r * N + c] = v;
    }
  }
}

// ---------------- Flash attention, causal GQA, fp32 (work-paired q-tiles) ----------------
__device__ __forceinline__ void attn_qtile(int qt, int h, int b,
    const float* __restrict__ qkv, float* __restrict__ attn_out,
    float (*Kt)[68], float (*Vt)[68]) {
  int g = h >> 1;
  int qcol = g * 256 + (h & 1) * 64;
  int kcol = g * 256 + 128;
  int vcol = g * 256 + 192;
  int tid = threadIdx.x;
  int r = tid >> 2, p = tid & 3;
  int sq = qt * 64 + r;
  float qv[16], o[16];
  const float* qrow = qkv + ((size_t)sq * BATCH + b) * QKV_OUT + qcol + p * 16;
#pragma unroll
  for (int i = 0; i < 16; i++) { qv[i] = qrow[i]; o[i] = 0.f; }
  float m = -1e30f, l = 0.f;
  for (int kt = 0; kt <= qt; kt++) {
#pragma unroll
    for (int i = 0; i < 16; i++) {
      int idx = tid + 256 * i;
      int rr = idx >> 6, cc = idx & 63;
      size_t base = ((size_t)(kt * 64 + rr) * BATCH + b) * QKV_OUT;
      Kt[rr][cc] = qkv[base + kcol + cc];
      Vt[rr][cc] = qkv[base + vcol + cc];
    }
    __syncthreads();
    float s[64];
#pragma unroll
    for (int j = 0; j < 64; j++) {
      float accd = 0.f;
#pragma unroll
      for (int i = 0; i < 16; i++) accd += qv[i] * Kt[j][p * 16 + i];
      accd += __shfl_xor(accd, 1);
      accd += __shfl_xor(accd, 2);
      s[j] = accd;
    }
    int kbase = kt * 64;
    float mt = -1e30f;
#pragma unroll
    for (int j = 0; j < 64; j++) {
      bool valid = (kbase + j) <= sq;
      s[j] = valid ? s[j] * 0.125f : -1e30f;
      mt = fmaxf(mt, s[j]);
    }
    float mn = fmaxf(m, mt);
    float corr = __expf(m - mn);
    l *= corr;
#pragma unroll
    for (int i = 0; i < 16; i++) o[i] *= corr;
#pragma unroll
    for (int j = 0; j < 64; j++) {
      float pj = __expf(s[j] - mn);
      l += pj;
#pragma unroll
      for (int i = 0; i < 16; i++) o[i] += pj * Vt[j][p * 16 + i];
    }
    m = mn;
    __syncthreads();
  }
  float inv = 1.f / l;
  float* orow = attn_out + ((size_t)sq * BATCH + b) * HIDDEN + h * 64 + p * 16;
#pragma unroll
  for (int i = 0; i < 16; i++) orow[i] = o[i] * inv;
}

__global__ __launch_bounds__(256) void attn_kernel(const float* __restrict__ qkv,
                                                   float* __restrict__ attn_out) {
  __shared__ float Kt[64][68];
  __shared__ float Vt[64][68];
  int pair = blockIdx.x, h = blockIdx.y, b = blockIdx.z;
  // q-tile `pair` has pair+1 k-tiles; q-tile `31-pair` has 32-pair: total 33 for every block.
  attn_qtile(pair, h, b, qkv, attn_out, Kt, Vt);
  __syncthreads();
  attn_qtile(31 - pair, h, b, qkv, attn_out, Kt, Vt);
}

// ---------------- bf16 MFMA GEMM: C[M,N] = A[M,K] @ B[N,K]^T ----------------
// 128x128 tile, BK=32, 4 waves (2x2 of 64x64), global_load_lds staging.
// EPI: 1 = gelu->bf16 out, 3 = f32 out
template<int EPI, bool GATHER>
__global__ __launch_bounds__(256) void gemm_bf16(
    const unsigned short* __restrict__ A, const unsigned short* __restrict__ B,
    const int* __restrict__ tok, void* __restrict__ Cout, int M, int N, int K,
    long sAz, long sBz, long sCz) {
  __shared__ __align__(16) unsigned short As[128 * 32];
  __shared__ __align__(16) unsigned short Bs[128 * 32];
  int tid = threadIdx.x, wid = tid >> 6, lane = tid & 63;
  int lr = lane & 15, lkg = lane >> 4;
  int bm = blockIdx.y, bn = blockIdx.x, bz = blockIdx.z;
  const unsigned short* Bb = B + (long)bz * sBz + (long)bn * 128 * K;
  int c0 = wid * 64 + lane;
  int r0 = c0 >> 2, r1 = r0 + 64;
  int ca = (c0 & 3) * 8;
  const unsigned short *pa0, *pa1;
  if (GATHER) {
    const int* tz = tok + (long)bz * M;
    int t0 = tz[bm * 128 + r0];
    int t1 = tz[bm * 128 + r1];
    pa0 = A + (long)t0 * K + ca;
    pa1 = A + (long)t1 * K + ca;
  } else {
    const unsigned short* Ab = A + (long)bz * sAz + (long)(bm * 128) * K;
    pa0 = Ab + (long)r0 * K + ca;
    pa1 = Ab + (long)r1 * K + ca;
  }
  const unsigned short* pb0 = Bb + (long)r0 * K + ca;
  const unsigned short* pb1 = Bb + (long)r1 * K + ca;
  unsigned short* lA0 = As + (wid * 64) * 8;
  unsigned short* lA1 = As + (wid * 64 + 256) * 8;
  unsigned short* lB0 = Bs + (wid * 64) * 8;
  unsigned short* lB1 = Bs + (wid * 64 + 256) * 8;
  int wr = (wid >> 1) * 64, wc = (wid & 1) * 64;
  f32x4 acc[4][4];
#pragma unroll
  for (int i = 0; i < 4; i++)
#pragma unroll
    for (int j = 0; j < 4; j++) acc[i][j] = (f32x4){0.f, 0.f, 0.f, 0.f};
  for (int k0 = 0; k0 < K; k0 += 32) {
    gl_lds16(pa0 + k0, lA0);
    gl_lds16(pa1 + k0, lA1);
    gl_lds16(pb0 + k0, lB0);
    gl_lds16(pb1 + k0, lB1);
    __syncthreads();
    bf16x8 af[4], bf[4];
#pragma unroll
    for (int m = 0; m < 4; m++)
      af[m] = *(const bf16x8*)(As + (wr + m * 16 + lr) * 32 + lkg * 8);
#pragma unroll
    for (int n = 0; n < 4; n++)
      bf[n] = *(const bf16x8*)(Bs + (wc + n * 16 + lr) * 32 + lkg * 8);
#pragma unroll
    for (int m = 0; m < 4; m++)
#pragma unroll
      for (int n = 0; n < 4; n++)
        acc[m][n] = mfma16(af[m], bf[n], acc[m][n]);
    __syncthreads();
  }
  long cz = (long)bz * sCz;
#pragma unroll
  for (int m = 0; m < 4; m++) {
    int crow = bm * 128 + wr + m * 16 + lkg * 4;
#pragma unroll
    for (int n = 0; n < 4; n++) {
      int ccol = bn * 128 + wc + n * 16 + lr;
#pragma unroll
      for (int r = 0; r < 4; r++) {
        float v = acc[m][n][r];
        long idx = cz + (long)(crow + r) * N + ccol;
        if (EPI == 1) {
          float gv = 0.5f * v * (1.f + erff(v * 0.70710678118654752440f));
          ((unsigned short*)Cout)[idx] = f2bu(gv);
        } else {
          ((float*)Cout)[idx] = v;
        }
      }
    }
  }
}

// ---------------- Router: fp32 logits, softmax, top-2, renormalize ----------------
__global__ __launch_bounds__(64) void router_kernel(const float* __restrict__ x,
    const float* __restrict__ wr, float* __restrict__ top_p, int* __restrict__ top_i) {
  int n = blockIdx.x;
  int lane = threadIdx.x;
  float acc[N_EXP];
#pragma unroll
  for (int e = 0; e < N_EXP; e++) acc[e] = 0.f;
  const float* xr = x + (long)n * HIDDEN;
  for (int hh = lane; hh < HIDDEN; hh += 64) {
    float xv = xr[hh];
    const float* wrow = wr + (long)hh * N_EXP;
#pragma unroll
    for (int e = 0; e < N_EXP; e++) acc[e] += xv * wrow[e];
  }
#pragma unroll
  for (int off = 32; off; off >>= 1)
#pragma unroll
    for (int e = 0; e < N_EXP; e++) acc[e] += __shfl_xor(acc[e], off);
  if (lane == 0) {
    float mx = acc[0];
#pragma unroll
    for (int e = 1; e < N_EXP; e++) mx = fmaxf(mx, acc[e]);
    float pr[N_EXP]; float ssum = 0.f;
#pragma unroll
    for (int e = 0; e < N_EXP; e++) { pr[e] = __expf(acc[e] - mx); ssum += pr[e]; }
    float inv = 1.f / ssum;
#pragma unroll
    for (int e = 0; e < N_EXP; e++) pr[e] *= inv;
    int i0 = 0; float p0 = pr[0];
#pragma unroll
    for (int e = 1; e < N_EXP; e++) if (pr[e] > p0) { p0 = pr[e]; i0 = e; }
    int i1 = -1; float p1 = -1.f;
#pragma unroll
    for (int e = 0; e < N_EXP; e++) if (e != i0 && pr[e] > p1) { p1 = pr[e]; i1 = e; }
    float norm = 1.f / (p0 + p1);
    top_p[n * 2] = p0 * norm;
    top_p[n * 2 + 1] = p1 * norm;
    top_i[n * 2] = i0;
    top_i[n * 2 + 1] = i1;
  }
}

// ---------------- Dispatch: stable per-expert rank ----------------
__global__ __launch_bounds__(64) void hist_kernel(const int* __restrict__ top_i,
    int* __restrict__ counts, int* __restrict__ wloc) {
  int i = blockIdx.x * 64 + threadIdx.x;
  int e = top_i[i];
  unsigned long long lower = (threadIdx.x == 0) ? 0ull : ((1ull << threadIdx.x) - 1ull);
  int wl = 0;
#pragma unroll
  for (int ex = 0; ex < N_EXP; ex++) {
    unsigned long long mmask = __ballot(e == ex);
    if (e == ex) wl = __popcll(mmask & lower);
    if ((int)threadIdx.x == ex) counts[blockIdx.x * N_EXP + ex] = __popcll(mmask);
  }
  wloc[i] = wl;
}

__global__ __launch_bounds__(64) void scan_kernel(const int* __restrict__ counts,
                                                  int* __restrict__ cbase) {
  int e = threadIdx.x;
  if (e < N_EXP) {
    int run = 0;
    for (int c = 0; c < NCHUNK; c++) {
      cbase[c * N_EXP + e] = run;
      run += counts[c * N_EXP + e];
    }
  }
}

__global__ __launch_bounds__(256) void assign_kernel(const int* __restrict__ top_i,
    const int* __restrict__ cbase, const int* __restrict__ wloc,
    int* __restrict__ soe, int* __restrict__ dtok) {
  int i = blockIdx.x * 256 + threadIdx.x;
  int e = top_i[i];
  int w = cbase[(i >> 6) * N_EXP + e] + wloc[i];
  if (w < CAP) {
    int slot = e * CAP + w;
    soe[i] = slot;
    dtok[slot] = i >> 1;
  } else {
    soe[i] = -1;
  }
}

// ---------------- Combine ----------------
__global__ __launch_bounds__(256) void combine_kernel(const float* __restrict__ hatt,
    const float* __restrict__ expo, const int* __restrict__ soe,
    const float* __restrict__ top_p, float* __restrict__ out) {
  int n = blockIdx.x;
  int s0 = soe[2 * n], s1 = soe[2 * n + 1];
  float p0 = top_p[2 * n], p1 = top_p[2 * n + 1];
#pragma unroll
  for (int i = 0; i < 4; i++) {
    int c = threadIdx.x + 256 * i;
    float v = hatt[(long)n * HIDDEN + c];
    if (s0 >= 0) v += p0 * expo[(long)s0 * HIDDEN + c];
    if (s1 >= 0) v += p1 * expo[(long)s1 * HIDDEN + c];
    out[(long)n * HIDDEN + c] = v;
  }
}

extern "C" void kernel_launch(void* const* d_in, const int* in_sizes, int n_in,
                              void* d_out, int out_size, void* d_ws, size_t ws_size,
                              hipStream_t stream) {
  const float* hidden = (const float*)d_in[0];
  const float* w_ln1 = (const float*)d_in[1];
  const float* b_ln1 = (const float*)d_in[2];
  const float* w_ln2 = (const float*)d_in[3];
  const float* b_ln2 = (const float*)d_in[4];
  const float* qkvW = (const float*)d_in[5];
  const float* projW = (const float*)d_in[6];
  const float* routW = (const float*)d_in[7];
  const float* w1 = (const float*)d_in[8];
  const float* w2 = (const float*)d_in[9];
  float* out = (float*)d_out;

  char* base = (char*)d_ws;
  size_t off = 0;
  auto alloc = [&](size_t bytes) -> void* {
    void* p = base + off;
    off = (off + bytes + 255) & ~(size_t)255;
    return p;
  };

  float* ln1f  = (float*)alloc((size_t)NTOK * HIDDEN * 4);
  float* qkvf  = (float*)alloc((size_t)NTOK * QKV_OUT * 4);
  float* attnf = (float*)alloc((size_t)NTOK * HIDDEN * 4);
  float* hattf = (float*)alloc((size_t)NTOK * HIDDEN * 4);
  float* x2f   = (float*)alloc((size_t)NTOK * HIDDEN * 4);
  unsigned short* x2b = (unsigned short*)alloc((size_t)NTOK * HIDDEN * 2);
  float* expo  = (float*)alloc((size_t)NSLOT * HIDDEN * 4);
  float* topp  = (float*)alloc(NFLAT * 4);
  int* topi    = (int*)alloc(NFLAT * 4);
  int* counts  = (int*)alloc(NCHUNK * N_EXP * 4);
  int* cbase   = (int*)alloc(NCHUNK * N_EXP * 4);
  int* wloc    = (int*)alloc(NFLAT * 4);
  int* soe     = (int*)alloc(NFLAT * 4);
  int* dtok    = (int*)alloc(NSLOT * 4);

  size_t common_end = off;
  size_t wtb = ((size_t)N_EXP * FFN * HIDDEN * 2 + 255) & ~(size_t)255;
  size_t actb = ((size_t)NSLOT * FFN * 2 + 255) & ~(size_t)255;
  bool full = ws_size >= common_end + 2 * wtb + actb;

  hipMemsetAsync(dtok, 0, NSLOT * 4, stream);

  // ---- attention half: all fp32 (router-feeding path must match fp32 reference) ----
  ln_kernel<false><<<NTOK, 256, 0, stream>>>(hidden, w_ln1, b_ln1, ln1f, nullptr);
  gemm_nt<false><<<dim3(QKV_OUT / 64, NTOK / 64), 256, 0, stream>>>(
      ln1f, qkvW, nullptr, qkvf, QKV_OUT, HIDDEN);
  attn_kernel<<<dim3(S_LEN / 128, N_HEADS, BATCH), 256, 0, stream>>>(qkvf, attnf);
  gemm_nt<true><<<dim3(HIDDEN / 64, NTOK / 64), 256, 0, stream>>>(
      attnf, projW, hidden, hattf, HIDDEN, HIDDEN);
  ln_kernel<true><<<NTOK, 256, 0, stream>>>(hattf, w_ln2, b_ln2, x2f, x2b);
  router_kernel<<<NTOK, 64, 0, stream>>>(x2f, routW, topp, topi);
  hist_kernel<<<NCHUNK, 64, 0, stream>>>(topi, counts, wloc);
  scan_kernel<<<1, 64, 0, stream>>>(counts, cbase);
  assign_kernel<<<NFLAT / 256, 256, 0, stream>>>(topi, cbase, wloc, soe, dtok);

  // ---- MoE half: routing fixed; expert GEMMs in bf16 MFMA ----
  if (full) {
    unsigned short* w1tb = (unsigned short*)alloc((size_t)N_EXP * FFN * HIDDEN * 2);
    unsigned short* w2tb = (unsigned short*)alloc((size_t)N_EXP * FFN * HIDDEN * 2);
    unsigned short* act  = (unsigned short*)alloc((size_t)NSLOT * FFN * 2);
    transpose_cvt<<<dim3(FFN / 32, HIDDEN / 32, N_EXP), 256, 0, stream>>>(w1, w1tb, HIDDEN, FFN);
    transpose_cvt<<<dim3(HIDDEN / 32, FFN / 32, N_EXP), 256, 0, stream>>>(w2, w2tb, FFN, HIDDEN);
    gemm_bf16<1, true><<<dim3(FFN / 128, CAP / 128, N_EXP), 256, 0, stream>>>(
        x2b, w1tb, dtok, act, CAP, FFN, HIDDEN,
        0, (long)FFN * HIDDEN, (long)CAP * FFN);
    gemm_bf16<3, false><<<dim3(HIDDEN / 128, CAP / 128, N_EXP), 256, 0, stream>>>(
        act, w2tb, nullptr, expo, CAP, HIDDEN, FFN,
        (long)CAP * FFN, (long)HIDDEN * FFN, (long)CAP * HIDDEN);
  } else {
    unsigned short* w1e = (unsigned short*)alloc((size_t)FFN * HIDDEN * 2);
    unsigned short* w2e = (unsigned short*)alloc((size_t)FFN * HIDDEN * 2);
    unsigned short* acte = (unsigned short*)alloc((size_t)CAP * FFN * 2);
    for (int e = 0; e < N_EXP; e++) {
      transpose_cvt<<<dim3(FFN / 32, HIDDEN / 32, 1), 256, 0, stream>>>(
          w1 + (long)e * HIDDEN * FFN, w1e, HIDDEN, FFN);
      gemm_bf16<1, true><<<dim3(FFN / 128, CAP / 128, 1), 256, 0, stream>>>(
          x2b, w1e, dtok + e * CAP, acte, CAP, FFN, HIDDEN, 0, 0, 0);
      transpose_cvt<<<dim3(HIDDEN / 32, FFN / 32, 1), 256, 0, stream>>>(
          w2 + (long)e * FFN * HIDDEN, w2e, FFN, HIDDEN);
      gemm_bf16<3, false><<<dim3(HIDDEN / 128, CAP / 128, 1), 256, 0, stream>>>(
          acte, w2e, nullptr, expo + (long)e * CAP * HIDDEN, CAP, HIDDEN, FFN, 0, 0, 0);
    }
  }
  combine_kernel<<<NTOK, 256, 0, stream>>>(hattf, expo, soe, topp, out);
}

// Round 11
// 1153.955 us; speedup vs baseline: 3.9500x; 1.5662x over previous
//
#include <hip/hip_runtime.h>
#include <math.h>

#define S_LEN   2048
#define BATCH   2
#define HIDDEN  1024
#define NTOK    4096
#define QKV_OUT 2048
#define N_HEADS 16
#define N_EXP   8
#define CAP     1280
#define NSLOT   10240
#define FFN     4096
#define NFLAT   8192
#define NCHUNK  128

typedef __bf16 bf16x8 __attribute__((ext_vector_type(8)));
typedef float f32x4 __attribute__((ext_vector_type(4)));
typedef unsigned short u16x4 __attribute__((ext_vector_type(4)));

__device__ __forceinline__ unsigned short f2bu(float f) {
  union { float f; unsigned u; } v; v.f = f;
  unsigned r = v.u + 0x7fffu + ((v.u >> 16) & 1u);
  return (unsigned short)(r >> 16);
}

__device__ __forceinline__ float b2f(unsigned short h) {
  union { unsigned u; float f; } v; v.u = (unsigned)h << 16; return v.f;
}

__device__ __forceinline__ void splitf(float x, unsigned short& hi, unsigned short& lo) {
  hi = f2bu(x);
  lo = f2bu(x - b2f(hi));
}

__device__ __forceinline__ f32x4 mfma16(bf16x8 a, bf16x8 b, f32x4 c) {
  return __builtin_amdgcn_mfma_f32_16x16x32_bf16(a, b, c, 0, 0, 0);
}

__device__ __forceinline__ void gl_lds16(const void* g, void* l) {
  __builtin_amdgcn_global_load_lds((const __attribute__((address_space(1))) void*)g,
                                   (__attribute__((address_space(3))) void*)l, 16, 0, 0);
}

union U8 { bf16x8 v; unsigned short s[8]; };

// ---------------- fp32 [R][C] -> bf16 [C][R] transposed convert (per z slice) ----------------
__global__ __launch_bounds__(256) void transpose_cvt(const float* __restrict__ in,
                                                     unsigned short* __restrict__ out,
                                                     int R, int C) {
  __shared__ float t[32][33];
  int c0 = blockIdx.x * 32, r0 = blockIdx.y * 32;
  long z = (long)blockIdx.z * R * C;
  const float* inz = in + z;
  unsigned short* outz = out + z;
  int x = threadIdx.x & 31, y0 = threadIdx.x >> 5;
#pragma unroll
  for (int i = 0; i < 4; i++) {
    int r = y0 + i * 8;
    t[r][x] = inz[(long)(r0 + r) * C + c0 + x];
  }
  __syncthreads();
#pragma unroll
  for (int i = 0; i < 4; i++) {
    int r = y0 + i * 8;
    outz[(long)(c0 + r) * R + r0 + x] = f2bu(t[x][r]);
  }
}

// ---------------- LayerNorm: fp32 in, fp32 out (+ optional bf16 out) ----------------
template<bool WB16>
__global__ __launch_bounds__(256) void ln_kernel(const float* __restrict__ in,
    const float* __restrict__ w, const float* __restrict__ bia,
    float* __restrict__ outf, unsigned short* __restrict__ outb) {
  int n = blockIdx.x, tid = threadIdx.x;
  float4 v = ((const float4*)(in + (long)n * HIDDEN))[tid];
  float s = v.x + v.y + v.z + v.w;
  float s2 = v.x * v.x + v.y * v.y + v.z * v.z + v.w * v.w;
#pragma unroll
  for (int off = 32; off; off >>= 1) { s += __shfl_xor(s, off); s2 += __shfl_xor(s2, off); }
  __shared__ float ss[4], ss2[4];
  int wv = tid >> 6;
  if ((tid & 63) == 0) { ss[wv] = s; ss2[wv] = s2; }
  __syncthreads();
  s = ss[0] + ss[1] + ss[2] + ss[3];
  s2 = ss2[0] + ss2[1] + ss2[2] + ss2[3];
  float mu = s * (1.f / HIDDEN);
  float var = s2 * (1.f / HIDDEN) - mu * mu;
  float rstd = rsqrtf(var + 1e-5f);
  float4 wv4 = ((const float4*)w)[tid];
  float4 bv4 = ((const float4*)bia)[tid];
  float4 of;
  of.x = (v.x - mu) * rstd * wv4.x + bv4.x;
  of.y = (v.y - mu) * rstd * wv4.y + bv4.y;
  of.z = (v.z - mu) * rstd * wv4.z + bv4.z;
  of.w = (v.w - mu) * rstd * wv4.w + bv4.w;
  *(float4*)(outf + (long)n * HIDDEN + tid * 4) = of;
  if (WB16) {
    u16x4 ob = { f2bu(of.x), f2bu(of.y), f2bu(of.z), f2bu(of.w) };
    *(u16x4*)(outb + (long)n * HIDDEN + tid * 4) = ob;
  }
}

// ---------------- fp32 GEMM: C[M,N] = A[M,K] @ B[N,K]^T (+ optional residual) ----------------
template<bool ADD_RES>
__global__ __launch_bounds__(256) void gemm_nt(const float* __restrict__ A,
    const float* __restrict__ B, const float* __restrict__ R, float* __restrict__ C,
    int N, int K) {
  __shared__ float As[16][68];
  __shared__ float Bs[16][68];
  int bx = blockIdx.x, by = blockIdx.y;
  int tid = threadIdx.x;
  int tx = tid & 15, ty = tid >> 4;
  int row0 = by * 64, col0 = bx * 64;
  float acc[4][4] = {};
  for (int k0 = 0; k0 < K; k0 += 16) {
#pragma unroll
    for (int i = 0; i < 4; i++) {
      int idx = tid + 256 * i;
      int r = idx >> 4, c = idx & 15;
      As[c][r] = A[(size_t)(row0 + r) * K + k0 + c];
      Bs[c][r] = B[(size_t)(col0 + r) * K + k0 + c];
    }
    __syncthreads();
#pragma unroll
    for (int kk = 0; kk < 16; kk++) {
      float a[4], bv[4];
#pragma unroll
      for (int i = 0; i < 4; i++) a[i] = As[kk][ty * 4 + i];
#pragma unroll
      for (int j = 0; j < 4; j++) bv[j] = Bs[kk][tx * 4 + j];
#pragma unroll
      for (int i = 0; i < 4; i++)
#pragma unroll
        for (int j = 0; j < 4; j++) acc[i][j] += a[i] * bv[j];
    }
    __syncthreads();
  }
#pragma unroll
  for (int i = 0; i < 4; i++) {
    int r = row0 + ty * 4 + i;
#pragma unroll
    for (int j = 0; j < 4; j++) {
      int c = col0 + tx * 4 + j;
      float v = acc[i][j];
      if (ADD_RES) v += R[(size_t)r * N + c];
      C[(size_t)r * N + c] = v;
    }
  }
}

// ---------------- Flash attention, causal GQA — compensated bf16 MFMA (hi/lo split) ----------------
// Error: residual ~1.6e-5 relative (vs 0.4% plain bf16) -> router-safe; softmax fp32.
// Block = 4 waves; wave w owns q-rows [qt*64+w*16, +16). K/V/P staged as hi+lo bf16 planes,
// 8-row XOR swizzle (byte ^= (row&7)<<4) on both write and read sides.
__device__ __forceinline__ void attn_hilo_qtile(int qt, int h, int b,
    const float* __restrict__ qkvf, float* __restrict__ attnf,
    unsigned short* Khi, unsigned short* Klo,
    unsigned short* Vhi, unsigned short* Vlo,
    unsigned short* Phi, unsigned short* Plo) {
  int g = h >> 1;
  int qcol = g * 256 + (h & 1) * 64, kcol = g * 256 + 128, vcol = g * 256 + 192;
  int tid = threadIdx.x, w = tid >> 6, lane = tid & 63;
  int lr = lane & 15, lkg = lane >> 4;
  // Q fragments (hi/lo), per wave: rows w*16+lr, d-halves [0,32) and [32,64)
  U8 qh[2], ql[2];
  {
    const float* qs = qkvf + ((long)(qt * 64 + w * 16 + lr) * BATCH + b) * QKV_OUT + qcol;
#pragma unroll
    for (int hf = 0; hf < 2; hf++) {
      float t0[8];
      ((float4*)t0)[0] = ((const float4*)(qs + hf * 32 + lkg * 8))[0];
      ((float4*)t0)[1] = ((const float4*)(qs + hf * 32 + lkg * 8))[1];
#pragma unroll
      for (int i = 0; i < 8; i++) {
        unsigned short hh, ll;
        splitf(t0[i], hh, ll);
        qh[hf].s[i] = hh; ql[hf].s[i] = ll;
      }
    }
  }
  f32x4 o[4];
  float m_[4], l_[4];
#pragma unroll
  for (int r = 0; r < 4; r++) { o[r] = (f32x4){0.f, 0.f, 0.f, 0.f}; m_[r] = -1e30f; l_[r] = 0.f; }
  for (int kt = 0; kt <= qt; ++kt) {
    // ---- K stage: row r_=tid>>2, cols dq..dq+15; hi/lo planes, swizzled ----
    {
      int r_ = tid >> 2, dq = (tid & 3) * 16;
      const float* ks = qkvf + ((long)(kt * 64 + r_) * BATCH + b) * QKV_OUT + kcol + dq;
      int sw = (r_ & 7) << 4;
#pragma unroll
      for (int jj = 0; jj < 4; jj++) {
        float4 kv = ((const float4*)ks)[jj];
        u16x4 h4, l4;
        unsigned short hh, ll;
        splitf(kv.x, hh, ll); h4[0] = hh; l4[0] = ll;
        splitf(kv.y, hh, ll); h4[1] = hh; l4[1] = ll;
        splitf(kv.z, hh, ll); h4[2] = hh; l4[2] = ll;
        splitf(kv.w, hh, ll); h4[3] = hh; l4[3] = ll;
        int byt = r_ * 128 + (((dq + jj * 4) * 2) ^ sw);
        *(u16x4*)((char*)Khi + byt) = h4;
        *(u16x4*)((char*)Klo + byt) = l4;
      }
    }
    // ---- V stage transposed: Vx[d][key], keys 2kp,2kp+1 packed per u32 ----
    {
      int kp = tid & 31, db = (tid >> 5) * 8;
      const float* v0 = qkvf + ((long)(kt * 64 + 2 * kp) * BATCH + b) * QKV_OUT + vcol + db;
      const float* v1 = v0 + (long)BATCH * QKV_OUT;
      float a0[8], a1[8];
      ((float4*)a0)[0] = ((const float4*)v0)[0];
      ((float4*)a0)[1] = ((const float4*)v0)[1];
      ((float4*)a1)[0] = ((const float4*)v1)[0];
      ((float4*)a1)[1] = ((const float4*)v1)[1];
#pragma unroll
      for (int i = 0; i < 8; i++) {
        int d = db + i;
        unsigned short h0, l0, h1, l1;
        splitf(a0[i], h0, l0);
        splitf(a1[i], h1, l1);
        int byt = d * 128 + ((kp * 4) ^ ((d & 7) << 4));
        *(unsigned*)((char*)Vhi + byt) = (unsigned)h0 | ((unsigned)h1 << 16);
        *(unsigned*)((char*)Vlo + byt) = (unsigned)l0 | ((unsigned)l1 << 16);
      }
    }
    __syncthreads();
    // ---- QK^T: 3-term compensated, 6 MFMA per 16-key subtile ----
    f32x4 sc[4];
#pragma unroll
    for (int ct = 0; ct < 4; ct++) {
      int krow = ct * 16 + lr;
      int sw = (krow & 7) << 4;
      bf16x8 kh0 = *(const bf16x8*)((const char*)Khi + krow * 128 + ((lkg * 16) ^ sw));
      bf16x8 kh1 = *(const bf16x8*)((const char*)Khi + krow * 128 + ((64 + lkg * 16) ^ sw));
      bf16x8 kl0 = *(const bf16x8*)((const char*)Klo + krow * 128 + ((lkg * 16) ^ sw));
      bf16x8 kl1 = *(const bf16x8*)((const char*)Klo + krow * 128 + ((64 + lkg * 16) ^ sw));
      f32x4 z = (f32x4){0.f, 0.f, 0.f, 0.f};
      z = mfma16(qh[0].v, kh0, z);
      z = mfma16(qh[1].v, kh1, z);
      z = mfma16(ql[0].v, kh0, z);
      z = mfma16(ql[1].v, kh1, z);
      z = mfma16(qh[0].v, kl0, z);
      z = mfma16(qh[1].v, kl1, z);
      sc[ct] = z;
    }
    // ---- online softmax (fp32); rows w*16+lkg*4+r, cols ct*16+lr ----
    float p_[4][4];
    int diag = (kt == qt);
#pragma unroll
    for (int ct = 0; ct < 4; ct++)
#pragma unroll
      for (int r = 0; r < 4; r++) {
        float s = sc[ct][r] * 0.125f;
        if (diag && (ct * 16 + lr) > (w * 16 + lkg * 4 + r)) s = -1e30f;
        p_[ct][r] = s;
      }
    float mt[4];
#pragma unroll
    for (int r = 0; r < 4; r++)
      mt[r] = fmaxf(fmaxf(p_[0][r], p_[1][r]), fmaxf(p_[2][r], p_[3][r]));
#pragma unroll
    for (int off = 1; off <= 8; off <<= 1)
#pragma unroll
      for (int r = 0; r < 4; r++) mt[r] = fmaxf(mt[r], __shfl_xor(mt[r], off));
    float rs[4];
#pragma unroll
    for (int r = 0; r < 4; r++) {
      float mn = fmaxf(m_[r], mt[r]);
      float corr = __expf(m_[r] - mn);
      m_[r] = mn;
      l_[r] *= corr;
#pragma unroll
      for (int dt = 0; dt < 4; dt++) o[dt][r] *= corr;
      float s = 0.f;
#pragma unroll
      for (int ct = 0; ct < 4; ct++) {
        float p = __expf(p_[ct][r] - mn);
        p_[ct][r] = p;
        s += p;
      }
      rs[r] = s;
    }
#pragma unroll
    for (int off = 1; off <= 8; off <<= 1)
#pragma unroll
      for (int r = 0; r < 4; r++) rs[r] += __shfl_xor(rs[r], off);
#pragma unroll
    for (int r = 0; r < 4; r++) l_[r] += rs[r];
    // ---- write P hi/lo (rows wave-private; swizzled) ----
#pragma unroll
    for (int r = 0; r < 4; r++) {
      int prow = w * 16 + lkg * 4 + r;
      int swp = (prow & 7) << 4;
#pragma unroll
      for (int ct = 0; ct < 4; ct++) {
        unsigned short hh, ll;
        splitf(p_[ct][r], hh, ll);
        int byt = prow * 128 + (((ct * 16 + lr) * 2) ^ swp);
        *(unsigned short*)((char*)Phi + byt) = hh;
        *(unsigned short*)((char*)Plo + byt) = ll;
      }
    }
    // ---- PV: 3-term compensated, 6 MFMA per 16-dim subtile ----
    bf16x8 ph0, ph1, pl0, pl1;
    {
      int prow = w * 16 + lr;
      int swp = (prow & 7) << 4;
      ph0 = *(const bf16x8*)((const char*)Phi + prow * 128 + ((lkg * 16) ^ swp));
      ph1 = *(const bf16x8*)((const char*)Phi + prow * 128 + ((64 + lkg * 16) ^ swp));
      pl0 = *(const bf16x8*)((const char*)Plo + prow * 128 + ((lkg * 16) ^ swp));
      pl1 = *(const bf16x8*)((const char*)Plo + prow * 128 + ((64 + lkg * 16) ^ swp));
    }
#pragma unroll
    for (int dt = 0; dt < 4; dt++) {
      int vrow = dt * 16 + lr;
      int swv = (vrow & 7) << 4;
      bf16x8 vh0 = *(const bf16x8*)((const char*)Vhi + vrow * 128 + ((lkg * 16) ^ swv));
      bf16x8 vh1 = *(const bf16x8*)((const char*)Vhi + vrow * 128 + ((64 + lkg * 16) ^ swv));
      bf16x8 vl0 = *(const bf16x8*)((const char*)Vlo + vrow * 128 + ((lkg * 16) ^ swv));
      bf16x8 vl1 = *(const bf16x8*)((const char*)Vlo + vrow * 128 + ((64 + lkg * 16) ^ swv));
      o[dt] = mfma16(ph0, vh0, o[dt]);
      o[dt] = mfma16(ph1, vh1, o[dt]);
      o[dt] = mfma16(pl0, vh0, o[dt]);
      o[dt] = mfma16(pl1, vh1, o[dt]);
      o[dt] = mfma16(ph0, vl0, o[dt]);
      o[dt] = mfma16(ph1, vl1, o[dt]);
    }
    __syncthreads();
  }
#pragma unroll
  for (int r = 0; r < 4; r++) {
    float inv = 1.f / l_[r];
    int sq = qt * 64 + w * 16 + lkg * 4 + r;
    float* orow = attnf + ((long)sq * BATCH + b) * HIDDEN + h * 64 + lr;
#pragma unroll
    for (int dt = 0; dt < 4; dt++) orow[dt * 16] = o[dt][r] * inv;
  }
}

__global__ __launch_bounds__(256) void attn_hilo(const float* __restrict__ qkvf,
                                                 float* __restrict__ attnf) {
  __shared__ __align__(16) unsigned short Khi[64 * 64], Klo[64 * 64];
  __shared__ __align__(16) unsigned short Vhi[64 * 64], Vlo[64 * 64];
  __shared__ __align__(16) unsigned short Phi[64 * 64], Plo[64 * 64];
  int pair = blockIdx.x, h = blockIdx.y, b = blockIdx.z;
  // pairing: qt=pair (pair+1 tiles) + qt=31-pair (32-pair tiles) = 33 per block, uniform
  attn_hilo_qtile(pair, h, b, qkvf, attnf, Khi, Klo, Vhi, Vlo, Phi, Plo);
  __syncthreads();
  attn_hilo_qtile(31 - pair, h, b, qkvf, attnf, Khi, Klo, Vhi, Vlo, Phi, Plo);
}

// ---------------- bf16 MFMA GEMM: C[M,N] = A[M,K] @ B[N,K]^T ----------------
// 128x128 tile, BK=32, 4 waves (2x2 of 64x64), global_load_lds staging.
// EPI: 1 = gelu->bf16 out, 3 = f32 out
template<int EPI, bool GATHER>
__global__ __launch_bounds__(256) void gemm_bf16(
    const unsigned short* __restrict__ A, const unsigned short* __restrict__ B,
    const int* __restrict__ tok, void* __restrict__ Cout, int M, int N, int K,
    long sAz, long sBz, long sCz) {
  __shared__ __align__(16) unsigned short As[128 * 32];
  __shared__ __align__(16) unsigned short Bs[128 * 32];
  int tid = threadIdx.x, wid = tid >> 6, lane = tid & 63;
  int lr = lane & 15, lkg = lane >> 4;
  int bm = blockIdx.y, bn = blockIdx.x, bz = blockIdx.z;
  const unsigned short* Bb = B + (long)bz * sBz + (long)bn * 128 * K;
  int c0 = wid * 64 + lane;
  int r0 = c0 >> 2, r1 = r0 + 64;
  int ca = (c0 & 3) * 8;
  const unsigned short *pa0, *pa1;
  if (GATHER) {
    const int* tz = tok + (long)bz * M;
    int t0 = tz[bm * 128 + r0];
    int t1 = tz[bm * 128 + r1];
    pa0 = A + (long)t0 * K + ca;
    pa1 = A + (long)t1 * K + ca;
  } else {
    const unsigned short* Ab = A + (long)bz * sAz + (long)(bm * 128) * K;
    pa0 = Ab + (long)r0 * K + ca;
    pa1 = Ab + (long)r1 * K + ca;
  }
  const unsigned short* pb0 = Bb + (long)r0 * K + ca;
  const unsigned short* pb1 = Bb + (long)r1 * K + ca;
  unsigned short* lA0 = As + (wid * 64) * 8;
  unsigned short* lA1 = As + (wid * 64 + 256) * 8;
  unsigned short* lB0 = Bs + (wid * 64) * 8;
  unsigned short* lB1 = Bs + (wid * 64 + 256) * 8;
  int wr = (wid >> 1) * 64, wc = (wid & 1) * 64;
  f32x4 acc[4][4];
#pragma unroll
  for (int i = 0; i < 4; i++)
#pragma unroll
    for (int j = 0; j < 4; j++) acc[i][j] = (f32x4){0.f, 0.f, 0.f, 0.f};
  for (int k0 = 0; k0 < K; k0 += 32) {
    gl_lds16(pa0 + k0, lA0);
    gl_lds16(pa1 + k0, lA1);
    gl_lds16(pb0 + k0, lB0);
    gl_lds16(pb1 + k0, lB1);
    __syncthreads();
    bf16x8 af[4], bf[4];
#pragma unroll
    for (int m = 0; m < 4; m++)
      af[m] = *(const bf16x8*)(As + (wr + m * 16 + lr) * 32 + lkg * 8);
#pragma unroll
    for (int n = 0; n < 4; n++)
      bf[n] = *(const bf16x8*)(Bs + (wc + n * 16 + lr) * 32 + lkg * 8);
#pragma unroll
    for (int m = 0; m < 4; m++)
#pragma unroll
      for (int n = 0; n < 4; n++)
        acc[m][n] = mfma16(af[m], bf[n], acc[m][n]);
    __syncthreads();
  }
  long cz = (long)bz * sCz;
#pragma unroll
  for (int m = 0; m < 4; m++) {
    int crow = bm * 128 + wr + m * 16 + lkg * 4;
#pragma unroll
    for (int n = 0; n < 4; n++) {
      int ccol = bn * 128 + wc + n * 16 + lr;
#pragma unroll
      for (int r = 0; r < 4; r++) {
        float v = acc[m][n][r];
        long idx = cz + (long)(crow + r) * N + ccol;
        if (EPI == 1) {
          float gv = 0.5f * v * (1.f + erff(v * 0.70710678118654752440f));
          ((unsigned short*)Cout)[idx] = f2bu(gv);
        } else {
          ((float*)Cout)[idx] = v;
        }
      }
    }
  }
}

// ---------------- Router: fp32 logits, softmax, top-2, renormalize ----------------
__global__ __launch_bounds__(64) void router_kernel(const float* __restrict__ x,
    const float* __restrict__ wr, float* __restrict__ top_p, int* __restrict__ top_i) {
  int n = blockIdx.x;
  int lane = threadIdx.x;
  float acc[N_EXP];
#pragma unroll
  for (int e = 0; e < N_EXP; e++) acc[e] = 0.f;
  const float* xr = x + (long)n * HIDDEN;
  for (int hh = lane; hh < HIDDEN; hh += 64) {
    float xv = xr[hh];
    const float* wrow = wr + (long)hh * N_EXP;
#pragma unroll
    for (int e = 0; e < N_EXP; e++) acc[e] += xv * wrow[e];
  }
#pragma unroll
  for (int off = 32; off; off >>= 1)
#pragma unroll
    for (int e = 0; e < N_EXP; e++) acc[e] += __shfl_xor(acc[e], off);
  if (lane == 0) {
    float mx = acc[0];
#pragma unroll
    for (int e = 1; e < N_EXP; e++) mx = fmaxf(mx, acc[e]);
    float pr[N_EXP]; float ssum = 0.f;
#pragma unroll
    for (int e = 0; e < N_EXP; e++) { pr[e] = __expf(acc[e] - mx); ssum += pr[e]; }
    float inv = 1.f / ssum;
#pragma unroll
    for (int e = 0; e < N_EXP; e++) pr[e] *= inv;
    int i0 = 0; float p0 = pr[0];
#pragma unroll
    for (int e = 1; e < N_EXP; e++) if (pr[e] > p0) { p0 = pr[e]; i0 = e; }
    int i1 = -1; float p1 = -1.f;
#pragma unroll
    for (int e = 0; e < N_EXP; e++) if (e != i0 && pr[e] > p1) { p1 = pr[e]; i1 = e; }
    float norm = 1.f / (p0 + p1);
    top_p[n * 2] = p0 * norm;
    top_p[n * 2 + 1] = p1 * norm;
    top_i[n * 2] = i0;
    top_i[n * 2 + 1] = i1;
  }
}

// ---------------- Dispatch: stable per-expert rank ----------------
__global__ __launch_bounds__(64) void hist_kernel(const int* __restrict__ top_i,
    int* __restrict__ counts, int* __restrict__ wloc) {
  int i = blockIdx.x * 64 + threadIdx.x;
  int e = top_i[i];
  unsigned long long lower = (threadIdx.x == 0) ? 0ull : ((1ull << threadIdx.x) - 1ull);
  int wl = 0;
#pragma unroll
  for (int ex = 0; ex < N_EXP; ex++) {
    unsigned long long mmask = __ballot(e == ex);
    if (e == ex) wl = __popcll(mmask & lower);
    if ((int)threadIdx.x == ex) counts[blockIdx.x * N_EXP + ex] = __popcll(mmask);
  }
  wloc[i] = wl;
}

__global__ __launch_bounds__(64) void scan_kernel(const int* __restrict__ counts,
                                                  int* __restrict__ cbase) {
  int e = threadIdx.x;
  if (e < N_EXP) {
    int run = 0;
    for (int c = 0; c < NCHUNK; c++) {
      cbase[c * N_EXP + e] = run;
      run += counts[c * N_EXP + e];
    }
  }
}

__global__ __launch_bounds__(256) void assign_kernel(const int* __restrict__ top_i,
    const int* __restrict__ cbase, const int* __restrict__ wloc,
    int* __restrict__ soe, int* __restrict__ dtok) {
  int i = blockIdx.x * 256 + threadIdx.x;
  int e = top_i[i];
  int w = cbase[(i >> 6) * N_EXP + e] + wloc[i];
  if (w < CAP) {
    int slot = e * CAP + w;
    soe[i] = slot;
    dtok[slot] = i >> 1;
  } else {
    soe[i] = -1;
  }
}

// ---------------- Combine ----------------
__global__ __launch_bounds__(256) void combine_kernel(const float* __restrict__ hatt,
    const float* __restrict__ expo, const int* __restrict__ soe,
    const float* __restrict__ top_p, float* __restrict__ out) {
  int n = blockIdx.x;
  int s0 = soe[2 * n], s1 = soe[2 * n + 1];
  float p0 = top_p[2 * n], p1 = top_p[2 * n + 1];
#pragma unroll
  for (int i = 0; i < 4; i++) {
    int c = threadIdx.x + 256 * i;
    float v = hatt[(long)n * HIDDEN + c];
    if (s0 >= 0) v += p0 * expo[(long)s0 * HIDDEN + c];
    if (s1 >= 0) v += p1 * expo[(long)s1 * HIDDEN + c];
    out[(long)n * HIDDEN + c] = v;
  }
}

extern "C" void kernel_launch(void* const* d_in, const int* in_sizes, int n_in,
                              void* d_out, int out_size, void* d_ws, size_t ws_size,
                              hipStream_t stream) {
  const float* hidden = (const float*)d_in[0];
  const float* w_ln1 = (const float*)d_in[1];
  const float* b_ln1 = (const float*)d_in[2];
  const float* w_ln2 = (const float*)d_in[3];
  const float* b_ln2 = (const float*)d_in[4];
  const float* qkvW = (const float*)d_in[5];
  const float* projW = (const float*)d_in[6];
  const float* routW = (const float*)d_in[7];
  const float* w1 = (const float*)d_in[8];
  const float* w2 = (const float*)d_in[9];
  float* out = (float*)d_out;

  char* base = (char*)d_ws;
  size_t off = 0;
  auto alloc = [&](size_t bytes) -> void* {
    void* p = base + off;
    off = (off + bytes + 255) & ~(size_t)255;
    return p;
  };

  float* ln1f  = (float*)alloc((size_t)NTOK * HIDDEN * 4);
  float* qkvf  = (float*)alloc((size_t)NTOK * QKV_OUT * 4);
  float* attnf = (float*)alloc((size_t)NTOK * HIDDEN * 4);
  float* hattf = (float*)alloc((size_t)NTOK * HIDDEN * 4);
  float* x2f   = (float*)alloc((size_t)NTOK * HIDDEN * 4);
  unsigned short* x2b = (unsigned short*)alloc((size_t)NTOK * HIDDEN * 2);
  float* expo  = (float*)alloc((size_t)NSLOT * HIDDEN * 4);
  float* topp  = (float*)alloc(NFLAT * 4);
  int* topi    = (int*)alloc(NFLAT * 4);
  int* counts  = (int*)alloc(NCHUNK * N_EXP * 4);
  int* cbase   = (int*)alloc(NCHUNK * N_EXP * 4);
  int* wloc    = (int*)alloc(NFLAT * 4);
  int* soe     = (int*)alloc(NFLAT * 4);
  int* dtok    = (int*)alloc(NSLOT * 4);

  size_t common_end = off;
  size_t wtb = ((size_t)N_EXP * FFN * HIDDEN * 2 + 255) & ~(size_t)255;
  size_t actb = ((size_t)NSLOT * FFN * 2 + 255) & ~(size_t)255;
  bool full = ws_size >= common_end + 2 * wtb + actb;

  hipMemsetAsync(dtok, 0, NSLOT * 4, stream);

  // ---- attention half: fp32 GEMMs; attention via hi/lo-compensated bf16 MFMA ----
  ln_kernel<false><<<NTOK, 256, 0, stream>>>(hidden, w_ln1, b_ln1, ln1f, nullptr);
  gemm_nt<false><<<dim3(QKV_OUT / 64, NTOK / 64), 256, 0, stream>>>(
      ln1f, qkvW, nullptr, qkvf, QKV_OUT, HIDDEN);
  attn_hilo<<<dim3(S_LEN / 128, N_HEADS, BATCH), 256, 0, stream>>>(qkvf, attnf);
  gemm_nt<true><<<dim3(HIDDEN / 64, NTOK / 64), 256, 0, stream>>>(
      attnf, projW, hidden, hattf, HIDDEN, HIDDEN);
  ln_kernel<true><<<NTOK, 256, 0, stream>>>(hattf, w_ln2, b_ln2, x2f, x2b);
  router_kernel<<<NTOK, 64, 0, stream>>>(x2f, routW, topp, topi);
  hist_kernel<<<NCHUNK, 64, 0, stream>>>(topi, counts, wloc);
  scan_kernel<<<1, 64, 0, stream>>>(counts, cbase);
  assign_kernel<<<NFLAT / 256, 256, 0, stream>>>(topi, cbase, wloc, soe, dtok);

  // ---- MoE half: routing fixed; expert GEMMs in bf16 MFMA ----
  if (full) {
    unsigned short* w1tb = (unsigned short*)alloc((size_t)N_EXP * FFN * HIDDEN * 2);
    unsigned short* w2tb = (unsigned short*)alloc((size_t)N_EXP * FFN * HIDDEN * 2);
    unsigned short* act  = (unsigned short*)alloc((size_t)NSLOT * FFN * 2);
    transpose_cvt<<<dim3(FFN / 32, HIDDEN / 32, N_EXP), 256, 0, stream>>>(w1, w1tb, HIDDEN, FFN);
    transpose_cvt<<<dim3(HIDDEN / 32, FFN / 32, N_EXP), 256, 0, stream>>>(w2, w2tb, FFN, HIDDEN);
    gemm_bf16<1, true><<<dim3(FFN / 128, CAP / 128, N_EXP), 256, 0, stream>>>(
        x2b, w1tb, dtok, act, CAP, FFN, HIDDEN,
        0, (long)FFN * HIDDEN, (long)CAP * FFN);
    gemm_bf16<3, false><<<dim3(HIDDEN / 128, CAP / 128, N_EXP), 256, 0, stream>>>(
        act, w2tb, nullptr, expo, CAP, HIDDEN, FFN,
        (long)CAP * FFN, (long)HIDDEN * FFN, (long)CAP * HIDDEN);
  } else {
    unsigned short* w1e = (unsigned short*)alloc((size_t)FFN * HIDDEN * 2);
    unsigned short* w2e = (unsigned short*)alloc((size_t)FFN * HIDDEN * 2);
    unsigned short* acte = (unsigned short*)alloc((size_t)CAP * FFN * 2);
    for (int e = 0; e < N_EXP; e++) {
      transpose_cvt<<<dim3(FFN / 32, HIDDEN / 32, 1), 256, 0, stream>>>(
          w1 + (long)e * HIDDEN * FFN, w1e, HIDDEN, FFN);
      gemm_bf16<1, true><<<dim3(FFN / 128, CAP / 128, 1), 256, 0, stream>>>(
          x2b, w1e, dtok + e * CAP, acte, CAP, FFN, HIDDEN, 0, 0, 0);
      transpose_cvt<<<dim3(HIDDEN / 32, FFN / 32, 1), 256, 0, stream>>>(
          w2 + (long)e * FFN * HIDDEN, w2e, FFN, HIDDEN);
      gemm_bf16<3, false><<<dim3(HIDDEN / 128, CAP / 128, 1), 256, 0, stream>>>(
          acte, w2e, nullptr, expo + (long)e * CAP * HIDDEN, CAP, HIDDEN, FFN, 0, 0, 0);
    }
  }
  combine_kernel<<<NTOK, 256, 0, stream>>>(hattf, expo, soe, topp, out);
}